// Round 1
// baseline (162.112 us; speedup 1.0000x reference)
//
#include <hip/hip_runtime.h>

#define Hh 512
#define Ww 512
#define Bb 2
#define Gg 4
#define Ff 9
#define Cc 3
#define Nn (Hh*Ww)

// Pass 1: normalize features over F and apply per-group FxF matrix -> fM (B,G,F,N)
__global__ void __launch_bounds__(256) fm_kernel(const float* __restrict__ img,
                                                 const float* __restrict__ M,
                                                 float* __restrict__ fM) {
    int p  = blockIdx.x * 256 + threadIdx.x;
    int bg = blockIdx.y;           // b*G+g
    int g  = bg & (Gg - 1);
    const float* src = img + (size_t)bg * Ff * Nn + p;
    float v[Ff];
    float ss = 0.f;
#pragma unroll
    for (int f = 0; f < Ff; ++f) { v[f] = src[f * Nn]; ss += v[f] * v[f]; }
    float inv = 1.0f / fmaxf(sqrtf(ss), 1e-12f);
#pragma unroll
    for (int f = 0; f < Ff; ++f) v[f] *= inv;
    const float* Mg = M + g * Ff * Ff;   // block-uniform -> scalar loads
    float* dst = fM + (size_t)bg * Ff * Nn + p;
#pragma unroll
    for (int vv = 0; vv < Ff; ++vv) {
        float acc = 0.f;
#pragma unroll
        for (int c = 0; c < Ff; ++c) acc = fmaf(v[c], Mg[c * Ff + vv], acc);
        dst[vv * Nn] = acc;
    }
}

// Pass 2: degree = sum of edge weights over 3x3 in-bounds window -> dinv (B,G,N)
__global__ void __launch_bounds__(256) deg_kernel(const float* __restrict__ fM,
                                                  float* __restrict__ dinv) {
    int p  = blockIdx.x * 256 + threadIdx.x;
    int bg = blockIdx.y;
    int y = p >> 9, x = p & (Ww - 1);
    const float* base = fM + (size_t)bg * Ff * Nn;
    float a[Ff];
#pragma unroll
    for (int f = 0; f < Ff; ++f) a[f] = base[f * Nn + p];
    float deg = 0.f;
#pragma unroll
    for (int dy = -1; dy <= 1; ++dy) {
        int yy = y + dy;
        if (yy < 0 || yy >= Hh) continue;
#pragma unroll
        for (int dx = -1; dx <= 1; ++dx) {
            int xx = x + dx;
            if (xx < 0 || xx >= Ww) continue;
            int q = yy * Ww + xx;
            float s = 0.f;
#pragma unroll
            for (int f = 0; f < Ff; ++f) s = fmaf(a[f], base[f * Nn + q], s);
            s = fminf(fmaxf(s, -10.f), 10.f);
            deg += __expf(s);
        }
    }
    dinv[(size_t)bg * Nn + p] = 1.0f / sqrtf(deg);
}

// Pass 3: out[c,p] = sig[c,p] - dinv[p]*sum_q ew(p,q)*dinv[q]*sig[c,q]
__global__ void __launch_bounds__(256) out_kernel(const float* __restrict__ fM,
                                                  const float* __restrict__ dinv,
                                                  const float* __restrict__ sig,
                                                  float* __restrict__ out) {
    int p  = blockIdx.x * 256 + threadIdx.x;
    int bg = blockIdx.y;
    int y = p >> 9, x = p & (Ww - 1);
    const float* base = fM + (size_t)bg * Ff * Nn;
    const float* dv   = dinv + (size_t)bg * Nn;
    const float* sg   = sig + (size_t)bg * Cc * Nn;
    float a[Ff];
#pragma unroll
    for (int f = 0; f < Ff; ++f) a[f] = base[f * Nn + p];
    float dp = dv[p];
    float agg0 = 0.f, agg1 = 0.f, agg2 = 0.f;
#pragma unroll
    for (int dy = -1; dy <= 1; ++dy) {
        int yy = y + dy;
        if (yy < 0 || yy >= Hh) continue;
#pragma unroll
        for (int dx = -1; dx <= 1; ++dx) {
            int xx = x + dx;
            if (xx < 0 || xx >= Ww) continue;
            int q = yy * Ww + xx;
            float s = 0.f;
#pragma unroll
            for (int f = 0; f < Ff; ++f) s = fmaf(a[f], base[f * Nn + q], s);
            s = fminf(fmaxf(s, -10.f), 10.f);
            float w = dp * __expf(s) * dv[q];
            agg0 = fmaf(w, sg[q], agg0);
            agg1 = fmaf(w, sg[Nn + q], agg1);
            agg2 = fmaf(w, sg[2 * Nn + q], agg2);
        }
    }
    float* o = out + (size_t)bg * Cc * Nn;
    o[p]          = sg[p]          - agg0;
    o[Nn + p]     = sg[Nn + p]     - agg1;
    o[2 * Nn + p] = sg[2 * Nn + p] - agg2;
}

extern "C" void kernel_launch(void* const* d_in, const int* in_sizes, int n_in,
                              void* d_out, int out_size, void* d_ws, size_t ws_size,
                              hipStream_t stream) {
    const float* img = (const float*)d_in[0];   // (B,G,F,H,W)
    const float* sig = (const float*)d_in[1];   // (B,G,C,H,W)
    const float* M   = (const float*)d_in[2];   // (G,F,F)
    // d_in[3..5] = edges/order/order_inverse: permutation cancels; unused.
    float* out  = (float*)d_out;
    float* fM   = (float*)d_ws;                           // B*G*F*N floats = 75.5 MB
    float* dinv = fM + (size_t)Bb * Gg * Ff * Nn;         // B*G*N floats   = 8.4 MB

    dim3 grid(Nn / 256, Bb * Gg);
    fm_kernel<<<grid, 256, 0, stream>>>(img, M, fM);
    deg_kernel<<<grid, 256, 0, stream>>>(fM, dinv);
    out_kernel<<<grid, 256, 0, stream>>>(fM, dinv, sig, out);
}

// Round 2
// 89.632 us; speedup vs baseline: 1.8086x; 1.8086x over previous
//
#include <hip/hip_runtime.h>

#define Hh 512
#define Ww 512
#define Bb 2
#define Gg 4
#define Ff 9
#define Cc 3
#define Nn (Hh*Ww)

#define TILE 32
#define RS 36          // fM region: tile + halo 2
#define DS 34          // deg region: tile + halo 1

// Fully fused: img -> fM (LDS, halo-2) -> dinv (LDS, halo-1) -> out (tile)
__global__ void __launch_bounds__(256) fused_kernel(const float* __restrict__ img,
                                                    const float* __restrict__ M,
                                                    const float* __restrict__ sig,
                                                    float* __restrict__ out) {
    __shared__ float fm[RS * RS * Ff];   // AoS stride 9 -> gcd(9,32)=1, conflict-free
    __shared__ float dv[DS * DS];

    const int tid = threadIdx.x;
    const int bg  = blockIdx.y;
    const int g   = bg & (Gg - 1);
    const int by0 = (blockIdx.x >> 4) * TILE;   // 16x16 tiles
    const int bx0 = (blockIdx.x & 15) * TILE;

    const float* imgP = img + (size_t)bg * Ff * Nn;
    const float* Mg   = M + g * Ff * Ff;        // block-uniform -> scalar path

    // ---- Phase 1: fM for 36x36 halo-2 region ----
    for (int i = tid; i < RS * RS; i += 256) {
        int r = (unsigned)i / RS, c = (unsigned)i - r * RS;
        int gy = by0 - 2 + r, gx = bx0 - 2 + c;
        if (gy >= 0 && gy < Hh && gx >= 0 && gx < Ww) {
            const float* src = imgP + gy * Ww + gx;
            float v[Ff]; float ss = 0.f;
#pragma unroll
            for (int f = 0; f < Ff; ++f) { v[f] = src[f * Nn]; ss += v[f] * v[f]; }
            float inv = 1.0f / fmaxf(sqrtf(ss), 1e-12f);
#pragma unroll
            for (int f = 0; f < Ff; ++f) v[f] *= inv;
            float* dst = &fm[i * Ff];
#pragma unroll
            for (int vv = 0; vv < Ff; ++vv) {
                float acc = 0.f;
#pragma unroll
                for (int cc = 0; cc < Ff; ++cc) acc = fmaf(v[cc], Mg[cc * Ff + vv], acc);
                dst[vv] = acc;
            }
        }
    }
    __syncthreads();

    // ---- Phase 2: dinv for 34x34 halo-1 region ----
    for (int i = tid; i < DS * DS; i += 256) {
        int r = (unsigned)i / DS, c = (unsigned)i - r * DS;
        int gy = by0 - 1 + r, gx = bx0 - 1 + c;
        if (gy >= 0 && gy < Hh && gx >= 0 && gx < Ww) {
            int fr = r + 1, fc = c + 1;         // coords in fM region
            const float* a = &fm[(fr * RS + fc) * Ff];
            float av[Ff];
#pragma unroll
            for (int f = 0; f < Ff; ++f) av[f] = a[f];
            float deg = 0.f;
#pragma unroll
            for (int dy = -1; dy <= 1; ++dy) {
                int yy = gy + dy;
                if (yy < 0 || yy >= Hh) continue;
#pragma unroll
                for (int dx = -1; dx <= 1; ++dx) {
                    int xx = gx + dx;
                    if (xx < 0 || xx >= Ww) continue;
                    const float* b = &fm[((fr + dy) * RS + (fc + dx)) * Ff];
                    float s = 0.f;
#pragma unroll
                    for (int f = 0; f < Ff; ++f) s = fmaf(av[f], b[f], s);
                    s = fminf(fmaxf(s, -10.f), 10.f);
                    deg += __expf(s);
                }
            }
            dv[i] = 1.0f / sqrtf(deg);
        }
    }
    __syncthreads();

    // ---- Phase 3: output for 32x32 interior ----
    const int tx = tid & 31;
    const int ty = tid >> 5;                    // 8 rows of threads
    const float* sg = sig + (size_t)bg * Cc * Nn;
    float* o = out + (size_t)bg * Cc * Nn;

#pragma unroll
    for (int k = 0; k < 4; ++k) {
        int row = ty + 8 * k;
        int gy = by0 + row, gx = bx0 + tx;
        int fr = row + 2, fc = tx + 2;
        const float* a = &fm[(fr * RS + fc) * Ff];
        float av[Ff];
#pragma unroll
        for (int f = 0; f < Ff; ++f) av[f] = a[f];
        float dp = dv[(row + 1) * DS + (tx + 1)];
        float agg0 = 0.f, agg1 = 0.f, agg2 = 0.f;
#pragma unroll
        for (int dy = -1; dy <= 1; ++dy) {
            int yy = gy + dy;
            if (yy < 0 || yy >= Hh) continue;
#pragma unroll
            for (int dx = -1; dx <= 1; ++dx) {
                int xx = gx + dx;
                if (xx < 0 || xx >= Ww) continue;
                const float* b = &fm[((fr + dy) * RS + (fc + dx)) * Ff];
                float s = 0.f;
#pragma unroll
                for (int f = 0; f < Ff; ++f) s = fmaf(av[f], b[f], s);
                s = fminf(fmaxf(s, -10.f), 10.f);
                float w = dp * __expf(s) * dv[(row + 1 + dy) * DS + (tx + 1 + dx)];
                int q = yy * Ww + xx;
                agg0 = fmaf(w, sg[q], agg0);
                agg1 = fmaf(w, sg[Nn + q], agg1);
                agg2 = fmaf(w, sg[2 * Nn + q], agg2);
            }
        }
        int p = gy * Ww + gx;
        o[p]          = sg[p]          - agg0;
        o[Nn + p]     = sg[Nn + p]     - agg1;
        o[2 * Nn + p] = sg[2 * Nn + p] - agg2;
    }
}

extern "C" void kernel_launch(void* const* d_in, const int* in_sizes, int n_in,
                              void* d_out, int out_size, void* d_ws, size_t ws_size,
                              hipStream_t stream) {
    const float* img = (const float*)d_in[0];   // (B,G,F,H,W)
    const float* sig = (const float*)d_in[1];   // (B,G,C,H,W)
    const float* M   = (const float*)d_in[2];   // (G,F,F)
    float* out = (float*)d_out;

    dim3 grid((Hh / TILE) * (Ww / TILE), Bb * Gg);   // 256 tiles x 8 planes
    fused_kernel<<<grid, 256, 0, stream>>>(img, M, sig, out);
}

// Round 3
// 63.242 us; speedup vs baseline: 2.5633x; 1.4173x over previous
//
#include <hip/hip_runtime.h>
#include <hip/hip_fp16.h>

#define Hh 512
#define Ww 512
#define Bb 2
#define Gg 4
#define Ff 9
#define Cc 3
#define Nn (Hh*Ww)

#define TILE 32
#define RS 36          // fM region: tile + halo 2
#define DS 34          // deg region: tile + halo 1
#define NT 512         // threads per block

// Fully fused: img -> fM (LDS half2 SoA, halo-2) -> dinv (LDS, halo-1) -> out (tile)
__global__ void __launch_bounds__(NT) fused_kernel(const float* __restrict__ img,
                                                   const float* __restrict__ M,
                                                   const float* __restrict__ sig,
                                                   float* __restrict__ out) {
    // 5 feature-pair planes (f8 padded with 0): lane-consecutive index -> bank stride 1
    __shared__ __half2 fm[5][RS * RS];
    __shared__ float dv[DS * DS];

    const int tid = threadIdx.x;
    const int bg  = blockIdx.y;
    const int g   = bg & (Gg - 1);
    const int by0 = (blockIdx.x >> 4) * TILE;   // 16x16 tiles
    const int bx0 = (blockIdx.x & 15) * TILE;

    const float* imgP = img + (size_t)bg * Ff * Nn;
    const float* Mg   = M + g * Ff * Ff;        // block-uniform -> scalar path

    // ---- Phase 1: fM (fp32 math, packed fp16 store) for 36x36 halo-2 region ----
    for (int i = tid; i < RS * RS; i += NT) {
        int r = (unsigned)i / RS, c = (unsigned)i - r * RS;
        int gy = by0 - 2 + r, gx = bx0 - 2 + c;
        if (gy >= 0 && gy < Hh && gx >= 0 && gx < Ww) {
            const float* src = imgP + gy * Ww + gx;
            float v[Ff]; float ss = 0.f;
#pragma unroll
            for (int f = 0; f < Ff; ++f) { v[f] = src[f * Nn]; ss += v[f] * v[f]; }
            float inv = 1.0f / fmaxf(sqrtf(ss), 1e-12f);
#pragma unroll
            for (int f = 0; f < Ff; ++f) v[f] *= inv;
            float m[Ff];
#pragma unroll
            for (int vv = 0; vv < Ff; ++vv) {
                float acc = 0.f;
#pragma unroll
                for (int cc = 0; cc < Ff; ++cc) acc = fmaf(v[cc], Mg[cc * Ff + vv], acc);
                m[vv] = acc;
            }
#pragma unroll
            for (int k = 0; k < 4; ++k)
                fm[k][i] = __floats2half2_rn(m[2 * k], m[2 * k + 1]);
            fm[4][i] = __floats2half2_rn(m[8], 0.f);
        }
    }
    __syncthreads();

    // ---- Phase 2: dinv for 34x34 halo-1 region ----
    for (int i = tid; i < DS * DS; i += NT) {
        int r = (unsigned)i / DS, c = (unsigned)i - r * DS;
        int gy = by0 - 1 + r, gx = bx0 - 1 + c;
        if (gy >= 0 && gy < Hh && gx >= 0 && gx < Ww) {
            int fi = (r + 1) * RS + (c + 1);    // coords in fM region
            __half2 a[5];
#pragma unroll
            for (int k = 0; k < 5; ++k) a[k] = fm[k][fi];
            float deg = 0.f;
#pragma unroll
            for (int dy = -1; dy <= 1; ++dy) {
                int yy = gy + dy;
                if (yy < 0 || yy >= Hh) continue;
#pragma unroll
                for (int dx = -1; dx <= 1; ++dx) {
                    int xx = gx + dx;
                    if (xx < 0 || xx >= Ww) continue;
                    int bi = fi + dy * RS + dx;
                    __half2 acc = __hmul2(a[0], fm[0][bi]);
#pragma unroll
                    for (int k = 1; k < 5; ++k) acc = __hfma2(a[k], fm[k][bi], acc);
                    float s = __low2float(acc) + __high2float(acc);
                    s = fminf(fmaxf(s, -10.f), 10.f);
                    deg += __expf(s);
                }
            }
            dv[i] = 1.0f / sqrtf(deg);
        }
    }
    __syncthreads();

    // ---- Phase 3: output for 32x32 interior (2 rows/thread) ----
    const int tx = tid & 31;
    const int ty = tid >> 5;                    // 16 rows of threads
    const float* sg = sig + (size_t)bg * Cc * Nn;
    float* o = out + (size_t)bg * Cc * Nn;

#pragma unroll
    for (int k = 0; k < 2; ++k) {
        int row = ty + 16 * k;
        int gy = by0 + row, gx = bx0 + tx;
        int fi = (row + 2) * RS + (tx + 2);
        __half2 a[5];
#pragma unroll
        for (int kk = 0; kk < 5; ++kk) a[kk] = fm[kk][fi];
        float dp = dv[(row + 1) * DS + (tx + 1)];
        float agg0 = 0.f, agg1 = 0.f, agg2 = 0.f;
#pragma unroll
        for (int dy = -1; dy <= 1; ++dy) {
            int yy = gy + dy;
            if (yy < 0 || yy >= Hh) continue;
#pragma unroll
            for (int dx = -1; dx <= 1; ++dx) {
                int xx = gx + dx;
                if (xx < 0 || xx >= Ww) continue;
                int bi = fi + dy * RS + dx;
                __half2 acc = __hmul2(a[0], fm[0][bi]);
#pragma unroll
                for (int kk = 1; kk < 5; ++kk) acc = __hfma2(a[kk], fm[kk][bi], acc);
                float s = __low2float(acc) + __high2float(acc);
                s = fminf(fmaxf(s, -10.f), 10.f);
                float w = dp * __expf(s) * dv[(row + 1 + dy) * DS + (tx + 1 + dx)];
                int q = yy * Ww + xx;
                agg0 = fmaf(w, sg[q], agg0);
                agg1 = fmaf(w, sg[Nn + q], agg1);
                agg2 = fmaf(w, sg[2 * Nn + q], agg2);
            }
        }
        int p = gy * Ww + gx;
        o[p]          = sg[p]          - agg0;
        o[Nn + p]     = sg[Nn + p]     - agg1;
        o[2 * Nn + p] = sg[2 * Nn + p] - agg2;
    }
}

extern "C" void kernel_launch(void* const* d_in, const int* in_sizes, int n_in,
                              void* d_out, int out_size, void* d_ws, size_t ws_size,
                              hipStream_t stream) {
    const float* img = (const float*)d_in[0];   // (B,G,F,H,W)
    const float* sig = (const float*)d_in[1];   // (B,G,C,H,W)
    const float* M   = (const float*)d_in[2];   // (G,F,F)
    float* out = (float*)d_out;

    dim3 grid((Hh / TILE) * (Ww / TILE), Bb * Gg);   // 256 tiles x 8 planes
    fused_kernel<<<grid, NT, 0, stream>>>(img, M, sig, out);
}

// Round 4
// 60.214 us; speedup vs baseline: 2.6923x; 1.0503x over previous
//
#include <hip/hip_runtime.h>
#include <hip/hip_fp16.h>

#define Hh 512
#define Ww 512
#define Bb 2
#define Gg 4
#define Ff 9
#define Cc 3
#define Nn (Hh*Ww)

#define TILE 32
#define RS 36          // fM region: tile + halo 2
#define DS 34          // deg/dinv region: tile + halo 1
#define NT 512         // threads per block

// Fused: img -> fM (LDS half2 SoA, halo-2) -> {deg/dinv LDS + ew in VGPRs} -> out
__global__ void __launch_bounds__(NT, 8) fused_kernel(const float* __restrict__ img,
                                                      const float* __restrict__ M,
                                                      const float* __restrict__ sig,
                                                      float* __restrict__ out) {
    __shared__ __half2 fm[5][RS * RS];   // 5 feature-pair planes, stride-1 banks
    __shared__ float dv[DS * DS];

    const int tid = threadIdx.x;
    const int bg  = blockIdx.y;
    const int g   = bg & (Gg - 1);
    const int by0 = (blockIdx.x >> 4) * TILE;   // 16x16 tiles
    const int bx0 = (blockIdx.x & 15) * TILE;

    const float* imgP = img + (size_t)bg * Ff * Nn;
    const float* Mg   = M + g * Ff * Ff;        // block-uniform -> scalar path

    // ---- Phase 1: fM (fp32 math, packed fp16 store) for 36x36 halo-2 region ----
    for (int i = tid; i < RS * RS; i += NT) {
        int r = (unsigned)i / RS, c = (unsigned)i - r * RS;
        int gy = by0 - 2 + r, gx = bx0 - 2 + c;
        if (gy >= 0 && gy < Hh && gx >= 0 && gx < Ww) {
            const float* src = imgP + gy * Ww + gx;
            float v[Ff]; float ss = 0.f;
#pragma unroll
            for (int f = 0; f < Ff; ++f) { v[f] = src[f * Nn]; ss += v[f] * v[f]; }
            float inv = 1.0f / fmaxf(sqrtf(ss), 1e-12f);
#pragma unroll
            for (int f = 0; f < Ff; ++f) v[f] *= inv;
            float m[Ff];
#pragma unroll
            for (int vv = 0; vv < Ff; ++vv) {
                float acc = 0.f;
#pragma unroll
                for (int cc = 0; cc < Ff; ++cc) acc = fmaf(v[cc], Mg[cc * Ff + vv], acc);
                m[vv] = acc;
            }
#pragma unroll
            for (int k = 0; k < 4; ++k)
                fm[k][i] = __floats2half2_rn(m[2 * k], m[2 * k + 1]);
            fm[4][i] = __floats2half2_rn(m[8], 0.f);
        }
    }
    __syncthreads();

    // ---- Phase 2a: interior 32x32 (2 px/thread): ew -> VGPRs, dinv -> LDS ----
    const int tx = tid & 31;
    const int ty = tid >> 5;                    // 16 thread-rows
    float ew[2][9];

#pragma unroll
    for (int k = 0; k < 2; ++k) {
        int row = ty + 16 * k;
        int gy = by0 + row, gx = bx0 + tx;      // always in-image
        int fi = (row + 2) * RS + (tx + 2);
        __half2 a[5];
#pragma unroll
        for (int kk = 0; kk < 5; ++kk) a[kk] = fm[kk][fi];
        float deg = 0.f;
#pragma unroll
        for (int dy = -1; dy <= 1; ++dy) {
#pragma unroll
            for (int dx = -1; dx <= 1; ++dx) {
                const int j = (dy + 1) * 3 + (dx + 1);
                int yy = gy + dy, xx = gx + dx;
                float e = 0.f;
                if (yy >= 0 && yy < Hh && xx >= 0 && xx < Ww) {
                    int bi = fi + dy * RS + dx;
                    __half2 acc = __hmul2(a[0], fm[0][bi]);
#pragma unroll
                    for (int kk = 1; kk < 5; ++kk) acc = __hfma2(a[kk], fm[kk][bi], acc);
                    float s = __low2float(acc) + __high2float(acc);
                    s = fminf(fmaxf(s, -10.f), 10.f);
                    e = __expf(s);
                    deg += e;
                }
                ew[k][j] = e;
            }
        }
        dv[(row + 1) * DS + (tx + 1)] = 1.0f / sqrtf(deg);
    }

    // ---- Phase 2b: halo ring (132 px): deg only ----
    if (tid < 132) {
        int r, c;
        if (tid < 34)       { r = 0;        c = tid;       }
        else if (tid < 68)  { r = 33;       c = tid - 34;  }
        else if (tid < 100) { r = tid - 67; c = 0;         }
        else                { r = tid - 99; c = 33;        }
        int gy = by0 - 1 + r, gx = bx0 - 1 + c;
        if (gy >= 0 && gy < Hh && gx >= 0 && gx < Ww) {
            int fi = (r + 1) * RS + (c + 1);
            __half2 a[5];
#pragma unroll
            for (int kk = 0; kk < 5; ++kk) a[kk] = fm[kk][fi];
            float deg = 0.f;
#pragma unroll
            for (int dy = -1; dy <= 1; ++dy) {
#pragma unroll
                for (int dx = -1; dx <= 1; ++dx) {
                    int yy = gy + dy, xx = gx + dx;
                    if (yy < 0 || yy >= Hh || xx < 0 || xx >= Ww) continue;
                    int bi = fi + dy * RS + dx;
                    __half2 acc = __hmul2(a[0], fm[0][bi]);
#pragma unroll
                    for (int kk = 1; kk < 5; ++kk) acc = __hfma2(a[kk], fm[kk][bi], acc);
                    float s = __low2float(acc) + __high2float(acc);
                    s = fminf(fmaxf(s, -10.f), 10.f);
                    deg += __expf(s);
                }
            }
            dv[r * DS + c] = 1.0f / sqrtf(deg);
        }
    }
    __syncthreads();

    // ---- Phase 3: output for 32x32 interior (no dots, no exp) ----
    const float* sg = sig + (size_t)bg * Cc * Nn;
    float* o = out + (size_t)bg * Cc * Nn;

#pragma unroll
    for (int k = 0; k < 2; ++k) {
        int row = ty + 16 * k;
        int gy = by0 + row, gx = bx0 + tx;
        float dp = dv[(row + 1) * DS + (tx + 1)];
        float agg0 = 0.f, agg1 = 0.f, agg2 = 0.f;
#pragma unroll
        for (int dy = -1; dy <= 1; ++dy) {
#pragma unroll
            for (int dx = -1; dx <= 1; ++dx) {
                const int j = (dy + 1) * 3 + (dx + 1);
                int yy = gy + dy, xx = gx + dx;
                if (yy < 0 || yy >= Hh || xx < 0 || xx >= Ww) continue;
                float w = dp * ew[k][j] * dv[(row + 1 + dy) * DS + (tx + 1 + dx)];
                int q = yy * Ww + xx;
                agg0 = fmaf(w, sg[q], agg0);
                agg1 = fmaf(w, sg[Nn + q], agg1);
                agg2 = fmaf(w, sg[2 * Nn + q], agg2);
            }
        }
        int p = gy * Ww + gx;
        o[p]          = sg[p]          - agg0;
        o[Nn + p]     = sg[Nn + p]     - agg1;
        o[2 * Nn + p] = sg[2 * Nn + p] - agg2;
    }
}

extern "C" void kernel_launch(void* const* d_in, const int* in_sizes, int n_in,
                              void* d_out, int out_size, void* d_ws, size_t ws_size,
                              hipStream_t stream) {
    const float* img = (const float*)d_in[0];   // (B,G,F,H,W)
    const float* sig = (const float*)d_in[1];   // (B,G,C,H,W)
    const float* M   = (const float*)d_in[2];   // (G,F,F)
    float* out = (float*)d_out;

    dim3 grid((Hh / TILE) * (Ww / TILE), Bb * Gg);   // 256 tiles x 8 planes
    fused_kernel<<<grid, NT, 0, stream>>>(img, M, sig, out);
}

// Round 5
// 59.241 us; speedup vs baseline: 2.7365x; 1.0164x over previous
//
#include <hip/hip_runtime.h>
#include <hip/hip_fp16.h>

#define Hh 512
#define Ww 512
#define Bb 2
#define Gg 4
#define Ff 9
#define Cc 3
#define Nn (Hh*Ww)

#define TILE 32
#define RS 36          // fM region: tile + halo 2
#define DS 34          // deg/dinv/sig region: tile + halo 1
#define NT 512         // threads per block

// Fused: img -> fm (LDS fp16, halo-2) -> {deg/dinv LDS + ew VGPR} -> out (branchless)
__global__ void __launch_bounds__(NT, 8) fused_kernel(const float* __restrict__ img,
                                                      const float* __restrict__ M,
                                                      const float* __restrict__ sig,
                                                      float* __restrict__ out) {
    __shared__ __half2 fmA[RS * RS][2];   // f0f1,f2f3  (16B/px -> b64/b128 reads)
    __shared__ __half2 fmB[RS * RS][2];   // f4f5,f6f7
    __shared__ __half2 fmC[RS * RS];      // f8,0
    __shared__ float   dv[DS * DS];       // 1/sqrt(deg); 1.0 in OOB slots
    __shared__ __half2 sg01[DS * DS];     // sig c0,c1 (0 in OOB slots)
    __shared__ __half  sg2[DS * DS];      // sig c2

    const int tid = threadIdx.x;
    const int bg  = blockIdx.y;
    const int g   = bg & (Gg - 1);
    const int by0 = (blockIdx.x >> 4) * TILE;   // 16x16 tiles
    const int bx0 = (blockIdx.x & 15) * TILE;

    const float* imgP = img + (size_t)bg * Ff * Nn;
    const float* sgp  = sig + (size_t)bg * Cc * Nn;
    const float* Mg   = M + g * Ff * Ff;        // block-uniform -> scalar path

    // ---- Phase 1a: stage sig tile (halo-1) into LDS as fp16, OOB -> 0 ----
    for (int i = tid; i < DS * DS; i += NT) {
        unsigned r = (unsigned)i / DS, c = (unsigned)i - r * DS;
        int gy = by0 - 1 + (int)r, gx = bx0 - 1 + (int)c;
        float v0 = 0.f, v1 = 0.f, v2 = 0.f;
        if ((unsigned)gy < Hh && (unsigned)gx < Ww) {
            int q = gy * Ww + gx;
            v0 = sgp[q]; v1 = sgp[Nn + q]; v2 = sgp[2 * Nn + q];
        }
        sg01[i] = __floats2half2_rn(v0, v1);
        sg2[i]  = __float2half_rn(v2);
    }

    // ---- Phase 1b: fm for 36x36 halo-2 region, OOB -> 0 ----
    for (int i = tid; i < RS * RS; i += NT) {
        unsigned r = (unsigned)i / RS, c = (unsigned)i - r * RS;
        int gy = by0 - 2 + (int)r, gx = bx0 - 2 + (int)c;
        float m[Ff];
        if ((unsigned)gy < Hh && (unsigned)gx < Ww) {
            const float* src = imgP + gy * Ww + gx;
            float v[Ff]; float ss = 0.f;
#pragma unroll
            for (int f = 0; f < Ff; ++f) { v[f] = src[f * Nn]; ss += v[f] * v[f]; }
            float inv = 1.0f / fmaxf(sqrtf(ss), 1e-12f);
#pragma unroll
            for (int f = 0; f < Ff; ++f) v[f] *= inv;
#pragma unroll
            for (int vv = 0; vv < Ff; ++vv) {
                float acc = 0.f;
#pragma unroll
                for (int cc = 0; cc < Ff; ++cc) acc = fmaf(v[cc], Mg[cc * Ff + vv], acc);
                m[vv] = acc;
            }
        } else {
#pragma unroll
            for (int f = 0; f < Ff; ++f) m[f] = 0.f;
        }
        fmA[i][0] = __floats2half2_rn(m[0], m[1]);
        fmA[i][1] = __floats2half2_rn(m[2], m[3]);
        fmB[i][0] = __floats2half2_rn(m[4], m[5]);
        fmB[i][1] = __floats2half2_rn(m[6], m[7]);
        fmC[i]    = __floats2half2_rn(m[8], 0.f);
    }
    __syncthreads();

    // ---- Phase 2a: interior 32x32 (2 px/thread): ew -> VGPRs, dinv -> LDS ----
    const int tx = tid & 31;
    const int ty = tid >> 5;                    // 16 thread-rows
    float ew[2][9];

#pragma unroll
    for (int k = 0; k < 2; ++k) {
        int row = ty + 16 * k;
        int gy = by0 + row, gx = bx0 + tx;      // always in-image
        int fi = (row + 2) * RS + (tx + 2);
        __half2 aA0 = fmA[fi][0], aA1 = fmA[fi][1];
        __half2 aB0 = fmB[fi][0], aB1 = fmB[fi][1];
        __half2 aC  = fmC[fi];
        float deg = 0.f;
#pragma unroll
        for (int dy = -1; dy <= 1; ++dy) {
#pragma unroll
            for (int dx = -1; dx <= 1; ++dx) {
                const int j = (dy + 1) * 3 + (dx + 1);
                int bi = fi + dy * RS + dx;
                __half2 acc = __hmul2(aA0, fmA[bi][0]);
                acc = __hfma2(aA1, fmA[bi][1], acc);
                acc = __hfma2(aB0, fmB[bi][0], acc);
                acc = __hfma2(aB1, fmB[bi][1], acc);
                acc = __hfma2(aC,  fmC[bi],    acc);
                float s = __low2float(acc) + __high2float(acc);
                s = fminf(fmaxf(s, -10.f), 10.f);
                float e = __expf(s);
                bool valid = ((unsigned)(gy + dy) < Hh) & ((unsigned)(gx + dx) < Ww);
                e = valid ? e : 0.f;
                ew[k][j] = e;
                deg += e;
            }
        }
        dv[(row + 1) * DS + (tx + 1)] = 1.0f / sqrtf(deg);
    }

    // ---- Phase 2b: halo ring (132 px): deg only; OOB slots -> 1.0 ----
    if (tid < 132) {
        int r, c;
        if (tid < 34)       { r = 0;        c = tid;       }
        else if (tid < 68)  { r = 33;       c = tid - 34;  }
        else if (tid < 100) { r = tid - 67; c = 0;         }
        else                { r = tid - 99; c = 33;        }
        int gy = by0 - 1 + r, gx = bx0 - 1 + c;
        float d = 1.0f;
        if ((unsigned)gy < Hh && (unsigned)gx < Ww) {
            int fi = (r + 1) * RS + (c + 1);
            __half2 aA0 = fmA[fi][0], aA1 = fmA[fi][1];
            __half2 aB0 = fmB[fi][0], aB1 = fmB[fi][1];
            __half2 aC  = fmC[fi];
            float deg = 0.f;
#pragma unroll
            for (int dy = -1; dy <= 1; ++dy) {
#pragma unroll
                for (int dx = -1; dx <= 1; ++dx) {
                    int bi = fi + dy * RS + dx;
                    __half2 acc = __hmul2(aA0, fmA[bi][0]);
                    acc = __hfma2(aA1, fmA[bi][1], acc);
                    acc = __hfma2(aB0, fmB[bi][0], acc);
                    acc = __hfma2(aB1, fmB[bi][1], acc);
                    acc = __hfma2(aC,  fmC[bi],    acc);
                    float s = __low2float(acc) + __high2float(acc);
                    s = fminf(fmaxf(s, -10.f), 10.f);
                    float e = __expf(s);
                    bool valid = ((unsigned)(gy + dy) < Hh) & ((unsigned)(gx + dx) < Ww);
                    deg += valid ? e : 0.f;
                }
            }
            d = 1.0f / sqrtf(deg);
        }
        dv[r * DS + c] = d;
    }
    __syncthreads();

    // ---- Phase 3: output for 32x32 interior — branchless, LDS-only inner loop ----
    float* o = out + (size_t)bg * Cc * Nn;

#pragma unroll
    for (int k = 0; k < 2; ++k) {
        int row = ty + 16 * k;
        int gy = by0 + row, gx = bx0 + tx;
        int di = (row + 1) * DS + (tx + 1);
        float dp = dv[di];
        float agg0 = 0.f, agg1 = 0.f, agg2 = 0.f;
#pragma unroll
        for (int dy = -1; dy <= 1; ++dy) {
#pragma unroll
            for (int dx = -1; dx <= 1; ++dx) {
                const int j = (dy + 1) * 3 + (dx + 1);
                int qi = di + dy * DS + dx;
                float w = dp * ew[k][j] * dv[qi];   // w==0 exactly for OOB neighbors
                __half2 s01 = sg01[qi];
                agg0 = fmaf(w, __low2float(s01),  agg0);
                agg1 = fmaf(w, __high2float(s01), agg1);
                agg2 = fmaf(w, __half2float(sg2[qi]), agg2);
            }
        }
        int p = gy * Ww + gx;
        o[p]          = sgp[p]          - agg0;
        o[Nn + p]     = sgp[Nn + p]     - agg1;
        o[2 * Nn + p] = sgp[2 * Nn + p] - agg2;
    }
}

extern "C" void kernel_launch(void* const* d_in, const int* in_sizes, int n_in,
                              void* d_out, int out_size, void* d_ws, size_t ws_size,
                              hipStream_t stream) {
    const float* img = (const float*)d_in[0];   // (B,G,F,H,W)
    const float* sig = (const float*)d_in[1];   // (B,G,C,H,W)
    const float* M   = (const float*)d_in[2];   // (G,F,F)
    float* out = (float*)d_out;

    dim3 grid((Hh / TILE) * (Ww / TILE), Bb * Gg);   // 256 tiles x 8 planes
    fused_kernel<<<grid, NT, 0, stream>>>(img, M, sig, out);
}

// Round 6
// 40.154 us; speedup vs baseline: 4.0373x; 1.4754x over previous
//
#include <hip/hip_runtime.h>
#include <hip/hip_fp16.h>

#define Hh 512
#define Ww 512
#define Bb 2
#define Gg 4
#define Ff 9
#define Cc 3
#define Nn (Hh*Ww)

#define TILE 32
#define RS 36          // fM region: tile + halo 2
#define DS 34          // deg/dinv/sig region: tile + halo 1
#define NT 256         // threads per block; each thread owns a 2x2 pixel quad

struct FmPt { __half2 a0, a1, b0, b1, c; };

__device__ __forceinline__ float dotfm(const FmPt& p, const FmPt& q) {
    __half2 acc = __hmul2(p.a0, q.a0);
    acc = __hfma2(p.a1, q.a1, acc);
    acc = __hfma2(p.b0, q.b0, acc);
    acc = __hfma2(p.b1, q.b1, acc);
    acc = __hfma2(p.c,  q.c,  acc);
    return __low2float(acc) + __high2float(acc);
}

__device__ __forceinline__ float ew_of(float s) {
    s = fminf(fmaxf(s, -10.f), 10.f);
    return __expf(s);
}

// phase-3 per-pixel aggregation: constant I0/J0/own e-array via macro -> static idx
#define PXOUT(ev, I0, J0, A0, A1, A2) do {                                   \
    __half2 agg01 = __floats2half2_rn(0.f, 0.f);                             \
    __half2 agg2v = __floats2half2_rn(0.f, 0.f);                             \
    float dp = dvf[((I0) + 1) * 4 + ((J0) + 1)];                             \
    _Pragma("unroll")                                                        \
    for (int j9 = 0; j9 < 9; ++j9) {                                         \
        int k = ((I0) + j9 / 3) * 4 + ((J0) + j9 % 3);                       \
        float wf = dp * ev[j9] * dvf[k];                                     \
        __half2 wh = __float2half2_rn(wf);                                   \
        agg01 = __hfma2(wh, s01[k], agg01);                                  \
        agg2v = __hfma2(wh, s2d[k], agg2v);  /* low=c2; high junk ignored */ \
    }                                                                        \
    A0 = __low2float(agg01); A1 = __high2float(agg01);                       \
    A2 = __low2float(agg2v);                                                 \
} while (0)

__global__ void __launch_bounds__(NT, 4) fused_kernel(const float* __restrict__ img,
                                                      const float* __restrict__ M,
                                                      const float* __restrict__ sig,
                                                      float* __restrict__ out) {
    __shared__ __half2 fmA[RS * RS][2];   // f0f1,f2f3
    __shared__ __half2 fmB[RS * RS][2];   // f4f5,f6f7
    __shared__ __half2 fmC[RS * RS];      // f8,0
    __shared__ __half  sgdv[DS * DS][4];  // c0,c1,c2,dinv (dinv filled in phase 2)

    const int tid = threadIdx.x;
    // XCD-plane swizzle: XCDs get blocks round-robin -> XCD i owns plane i,
    // tiles sequential within plane -> halo line reuse in XCD-private L2.
    const int bg   = blockIdx.x & 7;            // b*G+g
    const int tile = blockIdx.x >> 3;           // 0..255
    const int g    = bg & (Gg - 1);
    const int by0  = (tile >> 4) * TILE;
    const int bx0  = (tile & 15) * TILE;
    const bool border = (by0 == 0) | (by0 == Hh - TILE) | (bx0 == 0) | (bx0 == Ww - TILE);

    const float* imgP = img + (size_t)bg * Ff * Nn;
    const float* sgp  = sig + (size_t)bg * Cc * Nn;
    const float* Mg   = M + g * Ff * Ff;        // block-uniform -> scalar path

    auto LD = [&](int idx) -> FmPt {
        FmPt p;
        p.a0 = fmA[idx][0]; p.a1 = fmA[idx][1];
        p.b0 = fmB[idx][0]; p.b1 = fmB[idx][1];
        p.c  = fmC[idx];
        return p;
    };

    // ---- Phase 1a: stage sig tile (halo-1) into LDS fp16, OOB -> 0 ----
    for (int i = tid; i < DS * DS; i += NT) {
        unsigned r = (unsigned)i / DS, c = (unsigned)i - r * DS;
        int gy = by0 - 1 + (int)r, gx = bx0 - 1 + (int)c;
        float v0 = 0.f, v1 = 0.f, v2 = 0.f;
        if ((unsigned)gy < Hh && (unsigned)gx < Ww) {
            int q = gy * Ww + gx;
            v0 = sgp[q]; v1 = sgp[Nn + q]; v2 = sgp[2 * Nn + q];
        }
        *(__half2*)&sgdv[i][0] = __floats2half2_rn(v0, v1);
        *(__half2*)&sgdv[i][2] = __floats2half2_rn(v2, 0.f);
    }

    // ---- Phase 1b: fm for 36x36 halo-2 region, OOB -> 0 ----
    for (int i = tid; i < RS * RS; i += NT) {
        unsigned r = (unsigned)i / RS, c = (unsigned)i - r * RS;
        int gy = by0 - 2 + (int)r, gx = bx0 - 2 + (int)c;
        float m[Ff];
        if ((unsigned)gy < Hh && (unsigned)gx < Ww) {
            const float* src = imgP + gy * Ww + gx;
            float v[Ff]; float ss = 0.f;
#pragma unroll
            for (int f = 0; f < Ff; ++f) { v[f] = src[f * Nn]; ss += v[f] * v[f]; }
            float inv = 1.0f / fmaxf(sqrtf(ss), 1e-12f);
#pragma unroll
            for (int f = 0; f < Ff; ++f) v[f] *= inv;
#pragma unroll
            for (int vv = 0; vv < Ff; ++vv) {
                float acc = 0.f;
#pragma unroll
                for (int cc = 0; cc < Ff; ++cc) acc = fmaf(v[cc], Mg[cc * Ff + vv], acc);
                m[vv] = acc;
            }
        } else {
#pragma unroll
            for (int f = 0; f < Ff; ++f) m[f] = 0.f;
        }
        fmA[i][0] = __floats2half2_rn(m[0], m[1]);
        fmA[i][1] = __floats2half2_rn(m[2], m[3]);
        fmB[i][0] = __floats2half2_rn(m[4], m[5]);
        fmB[i][1] = __floats2half2_rn(m[6], m[7]);
        fmC[i]    = __floats2half2_rn(m[8], 0.f);
    }
    __syncthreads();

    // ---- Phase 2a: 2x2 quad per thread: 30 unique dots (6 shared), deg->dinv ----
    const int r2 = tid >> 4, c2 = tid & 15;
    const int gy0 = by0 + 2 * r2, gx0 = bx0 + 2 * c2;
    const int wb  = (2 * r2 + 1) * RS + (2 * c2 + 1);   // fm idx of window (0,0)

    FmPt w0[4], w1[4], w2[4], w3[4];
#pragma unroll
    for (int ci = 0; ci < 4; ++ci) w0[ci] = LD(wb + ci);
#pragma unroll
    for (int ci = 0; ci < 4; ++ci) w1[ci] = LD(wb + RS + ci);
#pragma unroll
    for (int ci = 0; ci < 4; ++ci) w2[ci] = LD(wb + 2 * RS + ci);

    float e0[9], e1[9], e2[9], e3[9];
    // px0 = w1[1]
    e0[0] = ew_of(dotfm(w1[1], w0[0])); e0[1] = ew_of(dotfm(w1[1], w0[1])); e0[2] = ew_of(dotfm(w1[1], w0[2]));
    e0[3] = ew_of(dotfm(w1[1], w1[0])); e0[4] = ew_of(dotfm(w1[1], w1[1])); e0[5] = ew_of(dotfm(w1[1], w1[2]));
    e0[6] = ew_of(dotfm(w1[1], w2[0])); e0[7] = ew_of(dotfm(w1[1], w2[1])); e0[8] = ew_of(dotfm(w1[1], w2[2]));
    // px1 = w1[2]  (shares W-edge with px0)
    e1[0] = ew_of(dotfm(w1[2], w0[1])); e1[1] = ew_of(dotfm(w1[2], w0[2])); e1[2] = ew_of(dotfm(w1[2], w0[3]));
    e1[3] = e0[5];                      e1[4] = ew_of(dotfm(w1[2], w1[2])); e1[5] = ew_of(dotfm(w1[2], w1[3]));
    e1[6] = ew_of(dotfm(w1[2], w2[1])); e1[7] = ew_of(dotfm(w1[2], w2[2])); e1[8] = ew_of(dotfm(w1[2], w2[3]));

#pragma unroll
    for (int ci = 0; ci < 4; ++ci) w3[ci] = LD(wb + 3 * RS + ci);   // w0 now dead

    // px2 = w2[1]  (shares N=e0.S, NE=e1.SW)
    e2[0] = ew_of(dotfm(w2[1], w1[0])); e2[1] = e0[7];                      e2[2] = e1[6];
    e2[3] = ew_of(dotfm(w2[1], w2[0])); e2[4] = ew_of(dotfm(w2[1], w2[1])); e2[5] = ew_of(dotfm(w2[1], w2[2]));
    e2[6] = ew_of(dotfm(w2[1], w3[0])); e2[7] = ew_of(dotfm(w2[1], w3[1])); e2[8] = ew_of(dotfm(w2[1], w3[2]));
    // px3 = w2[2]  (shares NW=e0.SE, N=e1.S, W=e2.E)
    e3[0] = e0[8];                      e3[1] = e1[7];                      e3[2] = ew_of(dotfm(w2[2], w1[3]));
    e3[3] = e2[5];                      e3[4] = ew_of(dotfm(w2[2], w2[2])); e3[5] = ew_of(dotfm(w2[2], w2[3]));
    e3[6] = ew_of(dotfm(w2[2], w3[1])); e3[7] = ew_of(dotfm(w2[2], w3[2])); e3[8] = ew_of(dotfm(w2[2], w3[3]));

    if (border) {   // mask edges leaving the image (shared edges never masked: both px interior)
#pragma unroll
        for (int j = 0; j < 9; ++j) {
            int dy = j / 3 - 1, dx = j % 3 - 1;
            if (!(((unsigned)(gy0 + dy)     < Hh) & ((unsigned)(gx0 + dx)     < Ww))) e0[j] = 0.f;
            if (!(((unsigned)(gy0 + dy)     < Hh) & ((unsigned)(gx0 + 1 + dx) < Ww))) e1[j] = 0.f;
            if (!(((unsigned)(gy0 + 1 + dy) < Hh) & ((unsigned)(gx0 + dx)     < Ww))) e2[j] = 0.f;
            if (!(((unsigned)(gy0 + 1 + dy) < Hh) & ((unsigned)(gx0 + 1 + dx) < Ww))) e3[j] = 0.f;
        }
    }

    float deg0 = 0.f, deg1 = 0.f, deg2 = 0.f, deg3 = 0.f;
#pragma unroll
    for (int j = 0; j < 9; ++j) { deg0 += e0[j]; deg1 += e1[j]; deg2 += e2[j]; deg3 += e3[j]; }
    {
        const int db = (2 * r2 + 1) * DS + (2 * c2 + 1);
        sgdv[db][3]          = __float2half_rn(1.0f / sqrtf(deg0));
        sgdv[db + 1][3]      = __float2half_rn(1.0f / sqrtf(deg1));
        sgdv[db + DS][3]     = __float2half_rn(1.0f / sqrtf(deg2));
        sgdv[db + DS + 1][3] = __float2half_rn(1.0f / sqrtf(deg3));
    }

    // ---- Phase 2b: halo ring (132 px): deg only; OOB slots -> 1.0 ----
    if (tid < 132) {
        int r, c;
        if (tid < 34)       { r = 0;        c = tid;       }
        else if (tid < 68)  { r = 33;       c = tid - 34;  }
        else if (tid < 100) { r = tid - 67; c = 0;         }
        else                { r = tid - 99; c = 33;        }
        int gy = by0 - 1 + r, gx = bx0 - 1 + c;
        float d = 1.0f;
        if ((unsigned)gy < Hh && (unsigned)gx < Ww) {
            int fi = (r + 1) * RS + (c + 1);
            FmPt a = LD(fi);
            float deg = 0.f;
#pragma unroll
            for (int j = 0; j < 9; ++j) {
                int dy = j / 3 - 1, dx = j % 3 - 1;
                FmPt q = LD(fi + dy * RS + dx);
                float e = ew_of(dotfm(a, q));
                bool valid = ((unsigned)(gy + dy) < Hh) & ((unsigned)(gx + dx) < Ww);
                deg += valid ? e : 0.f;
            }
            d = 1.0f / sqrtf(deg);
        }
        sgdv[r * DS + c][3] = __float2half_rn(d);
    }
    __syncthreads();

    // ---- Phase 3: 4x4 sig+dinv window (16 b64 reads), fp16 aggregation ----
    const int sb = 2 * r2 * DS + 2 * c2;   // ds idx of window (0,0)
    __half2 s01[16], s2d[16]; float dvf[16];
#pragma unroll
    for (int k = 0; k < 16; ++k) {
        int idx = sb + (k >> 2) * DS + (k & 3);
        s01[k] = *(const __half2*)&sgdv[idx][0];
        s2d[k] = *(const __half2*)&sgdv[idx][2];
        dvf[k] = __half2float(__high2half(s2d[k]));
    }

    float a00, a01, a02, a10, a11, a12, a20, a21, a22, a30, a31, a32;
    PXOUT(e0, 0, 0, a00, a01, a02);
    PXOUT(e1, 0, 1, a10, a11, a12);
    PXOUT(e2, 1, 0, a20, a21, a22);
    PXOUT(e3, 1, 1, a30, a31, a32);

    float* o = out + (size_t)bg * Cc * Nn;
    {
        int p = gy0 * Ww + gx0;                              // top pair (even col -> 8B aligned)
        float2 s0 = *(const float2*)&sgp[p];
        float2 s1 = *(const float2*)&sgp[Nn + p];
        float2 s2 = *(const float2*)&sgp[2 * Nn + p];
        *(float2*)&o[p]          = make_float2(s0.x - a00, s0.y - a10);
        *(float2*)&o[Nn + p]     = make_float2(s1.x - a01, s1.y - a11);
        *(float2*)&o[2 * Nn + p] = make_float2(s2.x - a02, s2.y - a12);
        p += Ww;                                             // bottom pair
        s0 = *(const float2*)&sgp[p];
        s1 = *(const float2*)&sgp[Nn + p];
        s2 = *(const float2*)&sgp[2 * Nn + p];
        *(float2*)&o[p]          = make_float2(s0.x - a20, s0.y - a30);
        *(float2*)&o[Nn + p]     = make_float2(s1.x - a21, s1.y - a31);
        *(float2*)&o[2 * Nn + p] = make_float2(s2.x - a22, s2.y - a32);
    }
}

extern "C" void kernel_launch(void* const* d_in, const int* in_sizes, int n_in,
                              void* d_out, int out_size, void* d_ws, size_t ws_size,
                              hipStream_t stream) {
    const float* img = (const float*)d_in[0];   // (B,G,F,H,W)
    const float* sig = (const float*)d_in[1];   // (B,G,C,H,W)
    const float* M   = (const float*)d_in[2];   // (G,F,F)
    float* out = (float*)d_out;

    fused_kernel<<<dim3(256 * Bb * Gg), NT, 0, stream>>>(img, M, sig, out);
}

// Round 7
// 38.032 us; speedup vs baseline: 4.2625x; 1.0558x over previous
//
#include <hip/hip_runtime.h>
#include <hip/hip_fp16.h>

#define Hh 512
#define Ww 512
#define Bb 2
#define Gg 4
#define Ff 9
#define Cc 3
#define Nn (Hh*Ww)

#define TILE 32
#define RS 36          // fM region: tile + halo 2
#define RSP 37         // padded row stride (bank-rotate)
#define DS 34          // deg/dinv region: tile + halo 1
#define DSP 35         // padded row stride
#define NT 256         // each thread owns a 2x2 pixel quad

struct FmPt { __half2 a0, a1, b0, b1; float cf; };

__device__ __forceinline__ float dotfm(const FmPt& p, const FmPt& q) {
    __half2 acc = __hmul2(p.a0, q.a0);
    acc = __hfma2(p.a1, q.a1, acc);
    acc = __hfma2(p.b0, q.b0, acc);
    acc = __hfma2(p.b1, q.b1, acc);
    return __low2float(acc) + __high2float(acc) + p.cf * q.cf;
}

__device__ __forceinline__ float ew_of(float s) {
    s = fminf(fmaxf(s, -10.f), 10.f);
    return __expf(s);
}

__global__ void __launch_bounds__(NT, 5) fused_kernel(const float* __restrict__ img,
                                                      const float* __restrict__ M,
                                                      const float* __restrict__ sig,
                                                      float* __restrict__ out) {
    __shared__ __half2 fmA[RS * RSP][2];   // f0f1,f2f3
    __shared__ __half2 fmB[RS * RSP][2];   // f4f5,f6f7
    __shared__ __half  fmC[RS * RSP];      // f8
    __shared__ float   dv[DS * DSP];       // 1/sqrt(deg); 1.0 in OOB slots

    const int tid = threadIdx.x;
    // XCD-plane swizzle: XCD i owns plane i; tiles sequential -> halo reuse in L2.
    const int bg   = blockIdx.x & 7;            // b*G+g
    const int tile = blockIdx.x >> 3;           // 0..255
    const int g    = bg & (Gg - 1);
    const int by0  = (tile >> 4) * TILE;
    const int bx0  = (tile & 15) * TILE;
    const bool border = (by0 == 0) | (by0 == Hh - TILE) | (bx0 == 0) | (bx0 == Ww - TILE);

    const float* imgP = img + (size_t)bg * Ff * Nn;
    const float* sgp  = sig + (size_t)bg * Cc * Nn;
    const float* Mg   = M + g * Ff * Ff;        // block-uniform -> scalar path

    auto LD = [&](int idx) -> FmPt {
        FmPt p;
        p.a0 = fmA[idx][0]; p.a1 = fmA[idx][1];
        p.b0 = fmB[idx][0]; p.b1 = fmB[idx][1];
        p.cf = __half2float(fmC[idx]);
        return p;
    };

    // ---- Phase 1: fm for 36x36 halo-2 region (padded stride), OOB -> 0 ----
    for (int i = tid; i < RS * RS; i += NT) {
        unsigned r = (unsigned)i / RS, c = (unsigned)i - r * RS;
        int gy = by0 - 2 + (int)r, gx = bx0 - 2 + (int)c;
        float m[Ff];
        if ((unsigned)gy < Hh && (unsigned)gx < Ww) {
            const float* src = imgP + gy * Ww + gx;
            float v[Ff]; float ss = 0.f;
#pragma unroll
            for (int f = 0; f < Ff; ++f) { v[f] = src[f * Nn]; ss += v[f] * v[f]; }
            float inv = 1.0f / fmaxf(sqrtf(ss), 1e-12f);
#pragma unroll
            for (int f = 0; f < Ff; ++f) v[f] *= inv;
#pragma unroll
            for (int vv = 0; vv < Ff; ++vv) {
                float acc = 0.f;
#pragma unroll
                for (int cc = 0; cc < Ff; ++cc) acc = fmaf(v[cc], Mg[cc * Ff + vv], acc);
                m[vv] = acc;
            }
        } else {
#pragma unroll
            for (int f = 0; f < Ff; ++f) m[f] = 0.f;
        }
        int si = r * RSP + c;
        fmA[si][0] = __floats2half2_rn(m[0], m[1]);
        fmA[si][1] = __floats2half2_rn(m[2], m[3]);
        fmB[si][0] = __floats2half2_rn(m[4], m[5]);
        fmB[si][1] = __floats2half2_rn(m[6], m[7]);
        fmC[si]    = __float2half_rn(m[8]);
    }
    __syncthreads();

    // ---- Phase 2a: 2x2 quad per thread: 30 unique dots (6 shared), deg->dinv ----
    const int r2 = tid >> 4, c2 = tid & 15;
    const int gy0 = by0 + 2 * r2, gx0 = bx0 + 2 * c2;
    const int wb  = (2 * r2 + 1) * RSP + (2 * c2 + 1);   // fm idx of window (0,0)

    FmPt w0[4], w1[4], w2[4], w3[4];
#pragma unroll
    for (int ci = 0; ci < 4; ++ci) w0[ci] = LD(wb + ci);
#pragma unroll
    for (int ci = 0; ci < 4; ++ci) w1[ci] = LD(wb + RSP + ci);
#pragma unroll
    for (int ci = 0; ci < 4; ++ci) w2[ci] = LD(wb + 2 * RSP + ci);

    float e0[9], e1[9], e2[9], e3[9];
    // px0 = w1[1]
    e0[0] = ew_of(dotfm(w1[1], w0[0])); e0[1] = ew_of(dotfm(w1[1], w0[1])); e0[2] = ew_of(dotfm(w1[1], w0[2]));
    e0[3] = ew_of(dotfm(w1[1], w1[0])); e0[4] = ew_of(dotfm(w1[1], w1[1])); e0[5] = ew_of(dotfm(w1[1], w1[2]));
    e0[6] = ew_of(dotfm(w1[1], w2[0])); e0[7] = ew_of(dotfm(w1[1], w2[1])); e0[8] = ew_of(dotfm(w1[1], w2[2]));
    // px1 = w1[2]  (shares W-edge with px0)
    e1[0] = ew_of(dotfm(w1[2], w0[1])); e1[1] = ew_of(dotfm(w1[2], w0[2])); e1[2] = ew_of(dotfm(w1[2], w0[3]));
    e1[3] = e0[5];                      e1[4] = ew_of(dotfm(w1[2], w1[2])); e1[5] = ew_of(dotfm(w1[2], w1[3]));
    e1[6] = ew_of(dotfm(w1[2], w2[1])); e1[7] = ew_of(dotfm(w1[2], w2[2])); e1[8] = ew_of(dotfm(w1[2], w2[3]));

#pragma unroll
    for (int ci = 0; ci < 4; ++ci) w3[ci] = LD(wb + 3 * RSP + ci);   // w0 now dead

    // px2 = w2[1]  (shares N=e0.S, NE=e1.SW)
    e2[0] = ew_of(dotfm(w2[1], w1[0])); e2[1] = e0[7];                      e2[2] = e1[6];
    e2[3] = ew_of(dotfm(w2[1], w2[0])); e2[4] = ew_of(dotfm(w2[1], w2[1])); e2[5] = ew_of(dotfm(w2[1], w2[2]));
    e2[6] = ew_of(dotfm(w2[1], w3[0])); e2[7] = ew_of(dotfm(w2[1], w3[1])); e2[8] = ew_of(dotfm(w2[1], w3[2]));
    // px3 = w2[2]  (shares NW=e0.SE, N=e1.S, W=e2.E)
    e3[0] = e0[8];                      e3[1] = e1[7];                      e3[2] = ew_of(dotfm(w2[2], w1[3]));
    e3[3] = e2[5];                      e3[4] = ew_of(dotfm(w2[2], w2[2])); e3[5] = ew_of(dotfm(w2[2], w2[3]));
    e3[6] = ew_of(dotfm(w2[2], w3[1])); e3[7] = ew_of(dotfm(w2[2], w3[2])); e3[8] = ew_of(dotfm(w2[2], w3[3]));

    if (border) {   // mask edges leaving the image
#pragma unroll
        for (int j = 0; j < 9; ++j) {
            int dy = j / 3 - 1, dx = j % 3 - 1;
            if (!(((unsigned)(gy0 + dy)     < Hh) & ((unsigned)(gx0 + dx)     < Ww))) e0[j] = 0.f;
            if (!(((unsigned)(gy0 + dy)     < Hh) & ((unsigned)(gx0 + 1 + dx) < Ww))) e1[j] = 0.f;
            if (!(((unsigned)(gy0 + 1 + dy) < Hh) & ((unsigned)(gx0 + dx)     < Ww))) e2[j] = 0.f;
            if (!(((unsigned)(gy0 + 1 + dy) < Hh) & ((unsigned)(gx0 + 1 + dx) < Ww))) e3[j] = 0.f;
        }
    }

    float deg0 = 0.f, deg1 = 0.f, deg2 = 0.f, deg3 = 0.f;
#pragma unroll
    for (int j = 0; j < 9; ++j) { deg0 += e0[j]; deg1 += e1[j]; deg2 += e2[j]; deg3 += e3[j]; }
    {
        const int db = (2 * r2 + 1) * DSP + (2 * c2 + 1);
        dv[db]           = 1.0f / sqrtf(deg0);
        dv[db + 1]       = 1.0f / sqrtf(deg1);
        dv[db + DSP]     = 1.0f / sqrtf(deg2);
        dv[db + DSP + 1] = 1.0f / sqrtf(deg3);
    }

    // ---- Phase 2b: halo ring (132 px): deg only; OOB slots -> 1.0 ----
    if (tid < 132) {
        int r, c;
        if (tid < 34)       { r = 0;        c = tid;       }
        else if (tid < 68)  { r = 33;       c = tid - 34;  }
        else if (tid < 100) { r = tid - 67; c = 0;         }
        else                { r = tid - 99; c = 33;        }
        int gy = by0 - 1 + r, gx = bx0 - 1 + c;
        float d = 1.0f;
        if ((unsigned)gy < Hh && (unsigned)gx < Ww) {
            int fi = (r + 1) * RSP + (c + 1);
            FmPt a = LD(fi);
            float deg = 0.f;
#pragma unroll
            for (int j = 0; j < 9; ++j) {
                int dy = j / 3 - 1, dx = j % 3 - 1;
                FmPt q = LD(fi + dy * RSP + dx);
                float e = ew_of(dotfm(a, q));
                bool valid = ((unsigned)(gy + dy) < Hh) & ((unsigned)(gx + dx) < Ww);
                deg += valid ? e : 0.f;
            }
            d = 1.0f / sqrtf(deg);
        }
        dv[r * DSP + c] = d;
    }
    __syncthreads();

    // ---- Phase 3: e -> w in regs; sig 4x4 window from global (L2-hot) ----
    float dvf[16];
    {
        const int db = 2 * r2 * DSP + 2 * c2;    // window (0,0) in dv coords
#pragma unroll
        for (int k = 0; k < 16; ++k)
            dvf[k] = dv[db + (k >> 2) * DSP + (k & 3)];
    }
    const float dp0 = dvf[5], dp1 = dvf[6], dp2 = dvf[9], dp3 = dvf[10];
#pragma unroll
    for (int j = 0; j < 9; ++j) {
        const int k0 = (j / 3) * 4 + (j % 3);
        e0[j] = dp0 * e0[j] * dvf[k0];
        e1[j] = dp1 * e1[j] * dvf[k0 + 1];
        e2[j] = dp2 * e2[j] * dvf[k0 + 4];
        e3[j] = dp3 * e3[j] * dvf[k0 + 5];
    }

    int ry[4], cx[4];
#pragma unroll
    for (int i = 0; i < 4; ++i) {
        ry[i] = min(max(gy0 - 1 + i, 0), Hh - 1) * Ww;   // clamped (w==0 kills OOB)
        cx[i] = min(max(gx0 - 1 + i, 0), Ww - 1);
    }

    float* o = out + (size_t)bg * Cc * Nn;
    const int p = gy0 * Ww + gx0;
#pragma unroll
    for (int ch = 0; ch < Cc; ++ch) {
        const float* sc = sgp + (size_t)ch * Nn;
        float s[16];
#pragma unroll
        for (int k = 0; k < 16; ++k) s[k] = sc[ry[k >> 2] + cx[k & 3]];
        float a0 = 0.f, a1 = 0.f, a2 = 0.f, a3 = 0.f;
#pragma unroll
        for (int j = 0; j < 9; ++j) {
            const int k0 = (j / 3) * 4 + (j % 3);
            a0 = fmaf(e0[j], s[k0],     a0);
            a1 = fmaf(e1[j], s[k0 + 1], a1);
            a2 = fmaf(e2[j], s[k0 + 4], a2);
            a3 = fmaf(e3[j], s[k0 + 5], a3);
        }
        float* oc = o + (size_t)ch * Nn;
        *(float2*)&oc[p]      = make_float2(s[5] - a0, s[6]  - a1);
        *(float2*)&oc[p + Ww] = make_float2(s[9] - a2, s[10] - a3);
    }
}

extern "C" void kernel_launch(void* const* d_in, const int* in_sizes, int n_in,
                              void* d_out, int out_size, void* d_ws, size_t ws_size,
                              hipStream_t stream) {
    const float* img = (const float*)d_in[0];   // (B,G,F,H,W)
    const float* sig = (const float*)d_in[1];   // (B,G,C,H,W)
    const float* M   = (const float*)d_in[2];   // (G,F,F)
    float* out = (float*)d_out;

    fused_kernel<<<dim3(256 * Bb * Gg), NT, 0, stream>>>(img, M, sig, out);
}